// Round 1
// 73.898 us; speedup vs baseline: 1.0607x; 1.0607x over previous
//
#include <hip/hip_runtime.h>

// Problem constants (fixed by the reference setup_inputs()).
#define F_DIM   1024   // in_features
#define O_DIM   1024   // out_features
#define W_DIM   7      // DEGREE - START_DEGREE + 1
#define BLOCK   256
#define RB      4      // rows per block: 1 row per wave, 4 waves

// Fused kernel, v2.
//   Changes vs v1 (78.4 us window, ~34 us kernel):
//   1. Epilogue no longer gathers coeffs from global with 112B lane stride
//      (~56 L1 transactions per load instr). Coeffs are staged ONCE per
//      block into LDS, TRANSPOSED to ct[w][o], so the epilogue reads
//      ct[w][4k..4k+3] as conflict-free ds_read_b128 (lane stride 16B).
//   2. Occupancy 2 -> 4 blocks/CU (8 -> 16 waves/CU): RB 8->4, one row per
//      wave, 1024 blocks. __launch_bounds__(256,4); LDS 28KiB*4 = 112KiB/CU.
//   3. x loads issued before staging so HBM latency overlaps the staging
//      loads and the barrier drain.
__global__ __launch_bounds__(BLOCK, 4) void hermite_fused(
    const float* __restrict__ x,       // (B, F)
    const float* __restrict__ coeffs,  // (O, W)
    const float* __restrict__ sigma,   // (1,)
    float* __restrict__ out)           // (B, O)
{
    const int tid  = threadIdx.x;
    const int lane = tid & 63;
    const int wave = tid >> 6;
    const int row  = blockIdx.x * RB + wave;   // this wave's row

    __shared__ float ct[W_DIM][O_DIM];         // transposed coeffs, 28 KiB

    // ---- issue this wave's x loads first (latency overlaps staging) ----
    const float4* xrow = (const float4*)(x + (size_t)row * F_DIM);
    float4 v[4];
    v[0] = xrow[lane];
    v[1] = xrow[lane + 64];
    v[2] = xrow[lane + 128];
    v[3] = xrow[lane + 192];

    // ---- stage coeffs transposed into LDS (one-time per block) ----
    // Thread t owns output columns o = 4t..4t+3, i.e. floats [28t, 28t+28)
    // of coeffs: 7 contiguous float4 loads (perfectly coalesced), then a
    // compile-time-indexed scatter ct[i%7][4t + i/7].
    {
        float tmp[28];
        const float4* cg = (const float4*)coeffs + 7 * tid;
#pragma unroll
        for (int j = 0; j < 7; ++j) {
            const float4 c4 = cg[j];
            tmp[4 * j + 0] = c4.x; tmp[4 * j + 1] = c4.y;
            tmp[4 * j + 2] = c4.z; tmp[4 * j + 3] = c4.w;
        }
        const int o0 = 4 * tid;
#pragma unroll
        for (int i = 0; i < 28; ++i)
            ct[i % 7][o0 + i / 7] = tmp[i];
    }

    const float s     = fminf(fmaxf(sigma[0], 0.1f), 5.0f);
    const float inv_s = 1.0f / s;

    __syncthreads();   // staging visible to all waves (also drains x loads)

    // ---- phase 1: Hermite basis for this wave's row ----
    float acc[W_DIM];
#pragma unroll
    for (int w = 0; w < W_DIM; ++w) acc[w] = 0.0f;

#pragma unroll
    for (int q = 0; q < 4; ++q) {
        const float el[4] = {v[q].x, v[q].y, v[q].z, v[q].w};
#pragma unroll
        for (int e = 0; e < 4; ++e) {
            const float xs = el[e] * inv_s;
            const float g  = __expf(-fminf(xs * xs, 50.0f));
            // H0=1, H1=2x, Hn = 2x*H_{n-1} - 2(n-1)*H_{n-2}; clip Hn
            // (n>=2) to [-100,100] before it feeds the next step (ref).
            float hm2 = 1.0f;
            float hm1 = 2.0f * xs;
            acc[0] += g;
            acc[1] += hm1 * g;
#pragma unroll
            for (int n = 2; n <= 6; ++n) {
                float hn = 2.0f * xs * hm1 - 2.0f * (float)(n - 1) * hm2;
                hn = fminf(fmaxf(hn, -100.0f), 100.0f);
                acc[n] += hn * g;
                hm2 = hm1;
                hm1 = hn;
            }
        }
    }

    // xor-butterfly: every lane ends with the full row sum
    float basis[W_DIM];
#pragma unroll
    for (int w = 0; w < W_DIM; ++w) {
        float a = acc[w];
#pragma unroll
        for (int m = 32; m > 0; m >>= 1)
            a += __shfl_xor(a, m, 64);
        basis[w] = a;
    }

    // ---- phase 2: epilogue from transposed LDS (conflict-free b128) ----
    float* orow = out + (size_t)row * O_DIM;
#pragma unroll
    for (int q = 0; q < 4; ++q) {
        const int k = q * 64 + lane;           // float4 index within the row
        float4 a;
        {
            const float4 c = *(const float4*)&ct[0][4 * k];
            a.x = basis[0] * c.x; a.y = basis[0] * c.y;
            a.z = basis[0] * c.z; a.w = basis[0] * c.w;
        }
#pragma unroll
        for (int w = 1; w < W_DIM; ++w) {
            const float4 c  = *(const float4*)&ct[w][4 * k];
            const float bw = basis[w];
            a.x = fmaf(bw, c.x, a.x);
            a.y = fmaf(bw, c.y, a.y);
            a.z = fmaf(bw, c.z, a.z);
            a.w = fmaf(bw, c.w, a.w);
        }
        ((float4*)orow)[k] = a;
    }
}

extern "C" void kernel_launch(void* const* d_in, const int* in_sizes, int n_in,
                              void* d_out, int out_size, void* d_ws, size_t ws_size,
                              hipStream_t stream) {
    const float* x      = (const float*)d_in[0];  // (B, F) fp32
    const float* coeffs = (const float*)d_in[1];  // (O, W) fp32
    const float* sigma  = (const float*)d_in[2];  // (1,)   fp32
    float* out          = (float*)d_out;          // (B, O) fp32

    const int B = in_sizes[0] / F_DIM;
    hermite_fused<<<dim3(B / RB), dim3(BLOCK), 0, stream>>>(x, coeffs, sigma, out);
}